// Round 19
// baseline (234.911 us; speedup 1.0000x reference)
//
#include <hip/hip_runtime.h>
#include <hip/hip_cooperative_groups.h>
#include <math.h>

namespace cg = cooperative_groups;

typedef __attribute__((ext_vector_type(8))) short bf16x8;
typedef __attribute__((ext_vector_type(16))) float f32x16;
typedef __attribute__((ext_vector_type(4))) unsigned int u32x4;

#define XB 131072   // x-halo LDS base; Kb stage slice occupies [0, 131072)

__device__ __forceinline__ unsigned f2bf(float f) {
    union { float f; unsigned u; } v; v.f = f;
    return (v.u + 0x7FFFu + ((v.u >> 16) & 1u)) >> 16;   // RTNE bf16
}

// counted wait: vmcnt(VM6) lgkmcnt(LG) (63/15 = no wait), then sched fence
template<int VM6, int LG>
__device__ __forceinline__ void waitcnt_fence() {
    __builtin_amdgcn_s_waitcnt((VM6 & 15) | ((VM6 >> 4) << 14) | (7 << 4) | (LG << 8));
    __builtin_amdgcn_sched_barrier(0);
}

// One K-step (pair P = taps 2P,2P+1; K=16 = 2 taps x 8 ch): prefetch pair
// P+1's A (2 reads) + B (2 reads) into 2-slot rings, lgkmcnt(4), then
// 4x mfma_32x32x16 on pair P. All LDS; no global ops in the loop.
// Halo strides: z=160 chunks, y=20, x=1 (chunk = 16B).
template<int P, int PLAST>
__device__ __forceinline__ void kstep2(
    const int (&nbase)[2], int abase, bool thv,
    bf16x8 (&Ar)[2][2], bf16x8 (&Br)[2][2], f32x16 (&acc)[2][2])
{
    if constexpr (P < PLAST) {
        constexpr int Q = P + 1;
        constexpr int t0 = 2 * Q;
        constexpr int t1 = (2 * Q + 1 == 125) ? 124 : 2 * Q + 1;  // B-alias pad tap
        constexpr int dA = ((t0 / 25) * 160 + ((t0 / 5) % 5) * 20 + (t0 % 5)) * 16;
        constexpr int dB = ((t1 / 25) * 160 + ((t1 / 5) % 5) * 20 + (t1 % 5)) * 16;
        #pragma unroll
        for (int mo = 0; mo < 2; ++mo) {
            int a = Q * 2048 + abase + mo * 512;
            asm volatile("ds_read_b128 %0, %1" : "=v"(Ar[Q & 1][mo]) : "v"(a));
        }
        int dsel = thv ? dB : dA;
        #pragma unroll
        for (int np = 0; np < 2; ++np) {
            int a = nbase[np] + dsel;
            asm volatile("ds_read_b128 %0, %1" : "=v"(Br[Q & 1][np]) : "v"(a));
        }
    }
    waitcnt_fence<63, (P < PLAST) ? 4 : 0>();
    #pragma unroll
    for (int mo = 0; mo < 2; ++mo)
        #pragma unroll
        for (int np = 0; np < 2; ++np)
            acc[mo][np] = __builtin_amdgcn_mfma_f32_32x32x16_bf16(
                Ar[P & 1][mo], Br[P & 1][np], acc[mo][np], 0, 0, 0);
    if constexpr (P < PLAST)
        kstep2<P + 1, PLAST>(nbase, abase, thv, Ar, Br, acc);
}

template<int P0, int PLAST>
__device__ __forceinline__ void runphase(
    const int (&nbase)[2], int abase, bool thv, f32x16 (&acc)[2][2])
{
    bf16x8 Ar[2][2], Br[2][2];
    constexpr int t0 = 2 * P0, t1 = 2 * P0 + 1;   // P0 in {0,32}: never 125
    constexpr int dA = ((t0 / 25) * 160 + ((t0 / 5) % 5) * 20 + (t0 % 5)) * 16;
    constexpr int dB = ((t1 / 25) * 160 + ((t1 / 5) % 5) * 20 + (t1 % 5)) * 16;
    #pragma unroll
    for (int mo = 0; mo < 2; ++mo) {
        int a = P0 * 2048 + abase + mo * 512;
        asm volatile("ds_read_b128 %0, %1" : "=v"(Ar[P0 & 1][mo]) : "v"(a));
    }
    int dsel = thv ? dB : dA;
    #pragma unroll
    for (int np = 0; np < 2; ++np) {
        int a = nbase[np] + dsel;
        asm volatile("ds_read_b128 %0, %1" : "=v"(Br[P0 & 1][np]) : "v"(a));
    }
    kstep2<P0, PLAST>(nbase, abase, thv, Ar, Br, acc);
}

// Fused cooperative kernel, grid 256 x 512 thr (1 block/CU):
//  phase 0 (prep): x -> channel-last bf16 xbz (LDS-transposed, 1KB-contig
//    wave writes; 2 sub-blocks per block) + build_K (blocks 0..63, tap =
//    2*blk+sub, 256-thr subgroups; zero-tap path barrier-symmetric).
//  __threadfence + grid.sync (device scope — cross-XCD visibility).
//  phase 1 (conv): round-18 structure verbatim: MFMA 32x32x16, all-LDS
//    operands, Kb 128KB HA/HB ping-pong DMA, x halo 30.7KB, T14 x-staging.
__global__ __launch_bounds__(512, 1) void fused(
    const float* __restrict__ w_lin0,
    const float* __restrict__ w_lin1,
    const float* __restrict__ tp_weight,
    unsigned short* __restrict__ Kb3,
    const float* __restrict__ x,
    unsigned short* __restrict__ xbz,
    float* __restrict__ out)
{
    __shared__ __align__(16) char lds[161792];   // conv: 128K Kb + 30720 x

    const int tid = (int)threadIdx.x;
    const int blk = (int)blockIdx.x;

    // ================= PHASE 0: prep =================
    {
        const int sub = tid >> 8;            // 256-thr subgroup 0/1
        const int stid = tid & 255;
        char* xpose = lds + sub * 32768;
        float* wshp = (float*)(lds + 65536 + sub * 8192);
        float* y1p  = (float*)(lds + 81920 + sub * 128);
        float* Qp   = y1p + 4;

        // ---- x transform: xblk = blk*2 + sub (0..511) ----
        const int xblk = blk * 2 + sub;
        if (xblk == 0 && stid < 64) xbz[stid] = 0;    // zero page
        const int p = xblk * 256 + stid;
        const int xb = p >> 15, pos = p & 32767;
        const float* xp = x + ((size_t)xb << 21) + pos;
        u32x4 dv[8];
        #pragma unroll
        for (int cgi = 0; cgi < 8; ++cgi) {
            #pragma unroll
            for (int jj = 0; jj < 4; ++jj) {
                float f0 = xp[((size_t)(cgi * 8 + 2 * jj)) << 15];
                float f1 = xp[((size_t)(cgi * 8 + 2 * jj + 1)) << 15];
                dv[cgi][jj] = f2bf(f0) | (f2bf(f1) << 16);
            }
        }
        #pragma unroll
        for (int cgi = 0; cgi < 8; ++cgi)
            *(u32x4*)&xpose[stid * 128 + ((cgi ^ (stid & 7)) << 4)] = dv[cgi];

        // ---- build_K pre-barrier part: blocks 0..63, tap = blk*2+sub ----
        const int tap = blk * 2 + sub;
        const bool doKb = (blk < 64);
        const bool kzero = (tap >= 125);
        if (doKb && !kzero) {
            const int i1 = tap / 25, i2 = (tap / 5) % 5, i3 = tap % 5;
            const float X = -1.0f + 0.5f * (float)i1;
            const float Y = -1.0f + 0.5f * (float)i2;
            const float Z = -1.0f + 0.5f * (float)i3;
            const float d = sqrtf(X*X + Y*Y + Z*Z);
            const float dinv = 1.0f / fmaxf(d, 1e-12f);
            const float vx = X * dinv, vy = Y * dinv, vz = Z * dinv;
            const float r2 = vx*vx + vy*vy + vz*vz;
            if (stid == 0) {
                const float s3 = 1.7320508075688772f;
                const float s15 = 3.872983346207417f;
                y1p[0] = s3 * vy; y1p[1] = s3 * vz; y1p[2] = s3 * vx;
                float y2v0 = s15 * vx * vy;
                float y2v1 = s15 * vy * vz;
                float y2v2 = 1.118033988749895f * (3.0f * vz * vz - r2);
                float y2v3 = s15 * vx * vz;
                float y2v4 = 1.9364916731037085f * (vx * vx - vy * vy);
                const float INV10 = 0.31622776601683794f;
                const float INV30 = 0.18257418583505536f;
                Qp[0] = -y2v2 * INV30 - y2v4 * INV10;
                Qp[4] =  2.0f * y2v2 * INV30;
                Qp[8] = -y2v2 * INV30 + y2v4 * INV10;
                Qp[1] = Qp[3] = y2v1 * INV10;
                Qp[2] = Qp[6] = y2v0 * INV10;
                Qp[5] = Qp[7] = y2v3 * INV10;
            }
            float emb[5];
            #pragma unroll
            for (int e = 0; e < 5; ++e) {
                float t = (d - 0.25f * (float)e) * 4.0f;
                emb[e] = expf(-t * t) * (1.0f / 1.12f);
            }
            const float scale = cosf(3.14159265358979323846f * d) / 11.180339887498949f;
            for (int j = stid; j < 1280; j += 256) {
                float s = 0.0f;
                #pragma unroll
                for (int e = 0; e < 5; ++e) s += emb[e] * tp_weight[e * 1280 + j];
                wshp[j] = scale * s;
            }
        }
        __syncthreads();

        // ---- x emit: wave-contiguous 1KB writes ----
        {
            const int w = tid >> 6, l = tid & 63, q = l >> 3, cgi = l & 7;
            char* xpw = lds + (w >> 2) * 32768;      // wave's subgroup tile
            const int xblkw = blk * 2 + (w >> 2);
            #pragma unroll
            for (int it = 0; it < 8; ++it) {
                int tsrc = (w & 3) * 64 + it * 8 + q;
                u32x4 c = *(const u32x4*)&xpw[tsrc * 128 + ((cgi ^ (tsrc & 7)) << 4)];
                *(u32x4*)((char*)xbz + 128 +
                          ((size_t)(xblkw * 256 + tsrc)) * 128 + cgi * 16) = c;
            }
        }

        // ---- build_K emit ----
        if (doKb) {
#define KIDX(o, i) ((((i) >> 3) * 128 + tap) * 512 + (o) * 8 + ((i) & 7))
            if (kzero) {
                for (int n = stid; n < 4096; n += 256)
                    Kb3[(n >> 9) * 65536 + tap * 512 + (n & 511)] = 0;
            } else {
                const float F0   = 0.17677669529663687f;
                const float F1   = 0.25f;
                const float F0S3 = 0.10206207261596574f;
                const float F1S3 = 0.14433756729740646f;
                #pragma unroll 1
                for (int n = 0; n < 16; ++n) {
                    int e = n * 256 + stid;
                    int o = e & 63, i = e >> 6;
                    float Kv;
                    if (o < 16) {
                        if (i < 16) {
                            Kv = F0 * wshp[0 * 256 + i * 16 + o];
                        } else {
                            int u = (i - 16) / 3, a = (i - 16) % 3;
                            Kv = F0S3 * y1p[a] * wshp[3 * 256 + u * 16 + o];
                        }
                    } else {
                        int wcol = (o - 16) / 3, c = (o - 16) % 3;
                        if (i < 16) {
                            Kv = F1S3 * y1p[c] * wshp[1 * 256 + i * 16 + wcol];
                        } else {
                            int u = (i - 16) / 3, a = (i - 16) % 3;
                            Kv = F1 * Qp[a * 3 + c] * wshp[4 * 256 + u * 16 + wcol];
                            if (a == c) Kv += F1S3 * wshp[2 * 256 + u * 16 + wcol];
                        }
                    }
                    if (tap == 62) {
                        if (o < 16) {
                            if (i < 16) Kv += 2.5f * w_lin0[i * 16 + o];
                        } else if (i >= 16) {
                            int v = (o - 16) / 3, m = (o - 16) % 3;
                            int u = (i - 16) / 3, a = (i - 16) % 3;
                            if (a == m) Kv += 2.5f * w_lin1[u * 16 + v];
                        }
                    }
                    Kb3[KIDX(o, i)] = (unsigned short)f2bf(Kv);
                }
            }
#undef KIDX
        }
    }

    __threadfence();                 // device-scope: publish xbz/Kb3 cross-XCD
    cg::this_grid().sync();

    // ================= PHASE 1: conv (round-18 verbatim) =================
    const int xt = blk & 1, yt = (blk >> 1) & 7, zt = (blk >> 4) & 3, b = blk >> 6;
    const int lane = tid & 63, wv = tid >> 6;
    const int l31 = lane & 31;
    const bool thv = (lane >= 32);

    // ---- x staging: 1920 chunks of 16B; 4 per thread (wrap duplicates) ----
    unsigned srcOff[4];
    int xdst[4];
    {
        const int gz0 = zt * 8 - 2, gy0 = yt * 4 - 2, gx0 = xt * 16 - 2;
        #pragma unroll
        for (int i = 0; i < 4; ++i) {
            int c = tid + i * 512;
            if (c >= 1920) c -= 1920;
            int hz = c / 160; int rem = c - hz * 160;
            int hy = rem / 20;  int hx = rem - hy * 20;
            int gz = gz0 + hz, gy = gy0 + hy, gx = gx0 + hx;
            bool ok = ((unsigned)gz < 32u) && ((unsigned)gy < 32u) && ((unsigned)gx < 32u);
            int pg = (gz << 10) + (gy << 5) + gx;
            srcOff[i] = ok ? (unsigned)(128 + (((b << 15) + pg) << 7)) : 0u;
            xdst[i] = XB + c * 16;
        }
    }

    // A-frag base: lane row o' = l31, k-half (tap-in-pair) = lane>=32
    const int abase = l31 * 16 + (thv ? 1024 : 0);
    // B-frag bases: pos col n = l31 -> y = (n>>4) + 2*np, x = n&15; z = wv
    int nbase[2];
    #pragma unroll
    for (int np = 0; np < 2; ++np)
        nbase[np] = XB + (wv * 160 + ((l31 >> 4) + 2 * np) * 20 + (l31 & 15)) * 16;

    f32x16 acc[2][2];
    #pragma unroll
    for (int i = 0; i < 2; ++i)
        #pragma unroll
        for (int j = 0; j < 2; ++j) acc[i][j] = (f32x16)0.0f;

    const char* kb = (const char*)Kb3;
    const int kchunk = tid * 16;       // thread's 16B lane within a 64KB half

    // prologue: HA(0) (taps 0..63 of stage 0) + x(0) via DMA
    #pragma unroll
    for (int j = 0; j < 8; ++j) {
        __builtin_amdgcn_global_load_lds(
            (const __attribute__((address_space(1))) unsigned int*)(kb + kchunk + j * 8192),
            (__attribute__((address_space(3))) unsigned int*)(lds + kchunk + j * 8192),
            16, 0, 0);
    }
    #pragma unroll
    for (int i = 0; i < 4; ++i) {
        __builtin_amdgcn_global_load_lds(
            (const __attribute__((address_space(1))) unsigned int*)
                ((const char*)xbz + srcOff[i]),
            (__attribute__((address_space(3))) unsigned int*)(lds + xdst[i]),
            16, 0, 0);
    }

    u32x4 xr[4];   // reg-staged x(s+1)

    #pragma unroll 1
    for (int s = 0; s < 8; ++s) {
        const char* kbs = kb + s * 131072;

        __builtin_amdgcn_s_barrier();               // B1: stage s-1 compute done
        __builtin_amdgcn_sched_barrier(0);
        if (s > 0) {
            waitcnt_fence<8, 15>();                 // xr landed (HA(s) may fly)
            #pragma unroll
            for (int i = 0; i < 4; ++i)
                asm volatile("ds_write_b128 %0, %1" :: "v"(xdst[i]), "v"(xr[i]));
        }
        // HB(s): taps 64..127
        #pragma unroll
        for (int j = 0; j < 8; ++j) {
            __builtin_amdgcn_global_load_lds(
                (const __attribute__((address_space(1))) unsigned int*)
                    (kbs + 65536 + kchunk + j * 8192),
                (__attribute__((address_space(3))) unsigned int*)
                    (lds + 65536 + kchunk + j * 8192),
                16, 0, 0);
        }
        waitcnt_fence<8, 0>();                      // HA(s) (+x) in; writes done
        __builtin_amdgcn_s_barrier();               // B2
        __builtin_amdgcn_sched_barrier(0);

        // xr <- x(s+1), full phase A of latency cover (s=7: dead reload, L2-hot)
        {
            unsigned sx = (unsigned)(((s < 7) ? s + 1 : 7) * 16);
            #pragma unroll
            for (int i = 0; i < 4; ++i) {
                unsigned voff = srcOff[i] + sx;
                asm volatile("global_load_dwordx4 %0, %1, %2"
                             : "=v"(xr[i]) : "v"(voff), "s"(xbz));
            }
            __builtin_amdgcn_sched_barrier(0);
        }

        runphase<0, 31>(nbase, abase, thv, acc);    // pairs 0..31 (HA)

        __builtin_amdgcn_s_barrier();               // B3: HA reads done
        __builtin_amdgcn_sched_barrier(0);
        // HA(s+1) (s=7: harmless overread into ws slack, never consumed)
        #pragma unroll
        for (int j = 0; j < 8; ++j) {
            __builtin_amdgcn_global_load_lds(
                (const __attribute__((address_space(1))) unsigned int*)
                    (kbs + 131072 + kchunk + j * 8192),
                (__attribute__((address_space(3))) unsigned int*)
                    (lds + kchunk + j * 8192),
                16, 0, 0);
        }
        waitcnt_fence<12, 15>();                    // HB(s) landed (xr+HA fly)
        __builtin_amdgcn_s_barrier();               // B4
        __builtin_amdgcn_sched_barrier(0);

        runphase<32, 62>(nbase, abase, thv, acc);   // pairs 32..62 (HB)
    }

    // epilogue: D col = pos = l31, row o' = (reg&3) + 8*(reg>>2) + 4*thv
    const int gz = zt * 8 + wv;
    #pragma unroll
    for (int mo = 0; mo < 2; ++mo) {
        #pragma unroll
        for (int np = 0; np < 2; ++np) {
            const int gy = yt * 4 + 2 * np + (l31 >> 4);
            const int gx = xt * 16 + (l31 & 15);
            #pragma unroll
            for (int reg = 0; reg < 16; ++reg) {
                int o = mo * 32 + (reg & 3) + 8 * (reg >> 2) + (thv ? 4 : 0);
                out[(((size_t)(b * 64 + o)) << 15) + (gz << 10) + (gy << 5) + gx] =
                    0.1f * acc[mo][np][reg];
            }
        }
    }
}

extern "C" void kernel_launch(void* const* d_in, const int* in_sizes, int n_in,
                              void* d_out, int out_size, void* d_ws, size_t ws_size,
                              hipStream_t stream) {
    const float* x       = (const float*)d_in[0];
    const float* w_lin0  = (const float*)d_in[1];
    const float* w_lin1  = (const float*)d_in[2];
    const float* tp      = (const float*)d_in[3];
    unsigned short* Kb3 = (unsigned short*)d_ws;                        // 1 MB (+slack)
    unsigned short* xbz = (unsigned short*)((char*)d_ws + (2u << 20));  // 128B zeros + 16.8MB
    float* out = (float*)d_out;

    void* args[] = { (void*)&w_lin0, (void*)&w_lin1, (void*)&tp,
                     (void*)&Kb3, (void*)&x, (void*)&xbz, (void*)&out };
    hipLaunchCooperativeKernel((const void*)fused, dim3(256), dim3(512),
                               args, 0, stream);
}

// Round 20
// 128.485 us; speedup vs baseline: 1.8283x; 1.8283x over previous
//
#include <hip/hip_runtime.h>
#include <math.h>

typedef __attribute__((ext_vector_type(8))) short bf16x8;
typedef __attribute__((ext_vector_type(16))) float f32x16;
typedef __attribute__((ext_vector_type(4))) unsigned int u32x4;

#define XB 131072   // x-halo LDS base; Kb stage slice occupies [0, 131072)

__device__ __forceinline__ unsigned f2bf(float f) {
    union { float f; unsigned u; } v; v.f = f;
    return (v.u + 0x7FFFu + ((v.u >> 16) & 1u)) >> 16;   // RTNE bf16
}

// counted wait: vmcnt(VM6) lgkmcnt(LG) (63/15 = no wait), then sched fence
template<int VM6, int LG>
__device__ __forceinline__ void waitcnt_fence() {
    __builtin_amdgcn_s_waitcnt((VM6 & 15) | ((VM6 >> 4) << 14) | (7 << 4) | (LG << 8));
    __builtin_amdgcn_sched_barrier(0);
}

// Merged prep kernel, grid 640 x 256 thr:
//  blocks 0..127   : build_K -> Kb3[stage][tap][o][8ch] (2KB per (stage,tap))
//  blocks 128..639 : to_blc  -> xbz channel-last bf16 with LDS-transposed
//                    1KB-contiguous wave writes.
__global__ __launch_bounds__(256) void prep(
    const float* __restrict__ w_lin0,
    const float* __restrict__ w_lin1,
    const float* __restrict__ tp_weight,
    unsigned short* __restrict__ Kb3,
    const float* __restrict__ x,
    unsigned short* __restrict__ xbz)
{
    __shared__ float wsh[1280];
    __shared__ float y1s[3];
    __shared__ float Qs[9];
    __shared__ __align__(16) char xpose[32768];

    const int tid = (int)threadIdx.x;
    const int blk = (int)blockIdx.x;

    if (blk < 128) {
        const int tap = blk;                    // 0..127
#define KIDX(o, i) ((((i) >> 3) * 128 + tap) * 512 + (o) * 8 + ((i) & 7))
        if (tap >= 125) {
            for (int n = tid; n < 4096; n += 256)
                Kb3[(n >> 9) * 65536 + tap * 512 + (n & 511)] = 0;
            return;
        }
        const int i1 = tap / 25, i2 = (tap / 5) % 5, i3 = tap % 5;
        const float X = -1.0f + 0.5f * (float)i1;
        const float Y = -1.0f + 0.5f * (float)i2;
        const float Z = -1.0f + 0.5f * (float)i3;
        const float d = sqrtf(X*X + Y*Y + Z*Z);
        const float dinv = 1.0f / fmaxf(d, 1e-12f);
        const float vx = X * dinv, vy = Y * dinv, vz = Z * dinv;
        const float r2 = vx*vx + vy*vy + vz*vz;

        if (tid == 0) {
            const float s3 = 1.7320508075688772f;
            const float s15 = 3.872983346207417f;
            y1s[0] = s3 * vy; y1s[1] = s3 * vz; y1s[2] = s3 * vx;
            float y2v0 = s15 * vx * vy;
            float y2v1 = s15 * vy * vz;
            float y2v2 = 1.118033988749895f * (3.0f * vz * vz - r2);
            float y2v3 = s15 * vx * vz;
            float y2v4 = 1.9364916731037085f * (vx * vx - vy * vy);
            const float INV10 = 0.31622776601683794f;
            const float INV30 = 0.18257418583505536f;
            Qs[0] = -y2v2 * INV30 - y2v4 * INV10;
            Qs[4] =  2.0f * y2v2 * INV30;
            Qs[8] = -y2v2 * INV30 + y2v4 * INV10;
            Qs[1] = Qs[3] = y2v1 * INV10;
            Qs[2] = Qs[6] = y2v0 * INV10;
            Qs[5] = Qs[7] = y2v3 * INV10;
        }

        float emb[5];
        #pragma unroll
        for (int e = 0; e < 5; ++e) {
            float t = (d - 0.25f * (float)e) * 4.0f;
            emb[e] = expf(-t * t) * (1.0f / 1.12f);
        }
        const float scale = cosf(3.14159265358979323846f * d) / 11.180339887498949f;

        for (int j = tid; j < 1280; j += 256) {
            float s = 0.0f;
            #pragma unroll
            for (int e = 0; e < 5; ++e) s += emb[e] * tp_weight[e * 1280 + j];
            wsh[j] = scale * s;
        }
        __syncthreads();

        const float F0   = 0.17677669529663687f;
        const float F1   = 0.25f;
        const float F0S3 = 0.10206207261596574f;
        const float F1S3 = 0.14433756729740646f;

        #pragma unroll 1
        for (int n = 0; n < 16; ++n) {
            int e = n * 256 + tid;
            int o = e & 63, i = e >> 6;
            float Kv;
            if (o < 16) {
                if (i < 16) {
                    Kv = F0 * wsh[0 * 256 + i * 16 + o];
                } else {
                    int u = (i - 16) / 3, a = (i - 16) % 3;
                    Kv = F0S3 * y1s[a] * wsh[3 * 256 + u * 16 + o];
                }
            } else {
                int wcol = (o - 16) / 3, c = (o - 16) % 3;
                if (i < 16) {
                    Kv = F1S3 * y1s[c] * wsh[1 * 256 + i * 16 + wcol];
                } else {
                    int u = (i - 16) / 3, a = (i - 16) % 3;
                    Kv = F1 * Qs[a * 3 + c] * wsh[4 * 256 + u * 16 + wcol];
                    if (a == c) Kv += F1S3 * wsh[2 * 256 + u * 16 + wcol];
                }
            }
            if (tap == 62) {
                if (o < 16) {
                    if (i < 16) Kv += 2.5f * w_lin0[i * 16 + o];
                } else if (i >= 16) {
                    int v = (o - 16) / 3, m = (o - 16) % 3;
                    int u = (i - 16) / 3, a = (i - 16) % 3;
                    if (a == m) Kv += 2.5f * w_lin1[u * 16 + v];
                }
            }
            Kb3[KIDX(o, i)] = (unsigned short)f2bf(Kv);
        }
#undef KIDX
        return;
    }

    // ---- to_blc with LDS transpose ----
    const int blk2 = blk - 128;                  // 0..511
    if (blk2 == 0 && tid < 64) xbz[tid] = 0;     // zero page
    const int p = blk2 * 256 + tid;              // pos index (b*32768+pos)
    const int b = p >> 15, pos = p & 32767;
    const float* xp = x + ((size_t)b << 21) + pos;

    u32x4 dv[8];
    #pragma unroll
    for (int cg = 0; cg < 8; ++cg) {
        #pragma unroll
        for (int jj = 0; jj < 4; ++jj) {
            float f0 = xp[((size_t)(cg * 8 + 2 * jj)) << 15];
            float f1 = xp[((size_t)(cg * 8 + 2 * jj + 1)) << 15];
            dv[cg][jj] = f2bf(f0) | (f2bf(f1) << 16);
        }
    }
    // stage: thread t's chunk cg at t*128 + (cg ^ (t&7))*16  (swizzle ->
    // each 8-lane group covers all 32 banks exactly once on write & read)
    #pragma unroll
    for (int cg = 0; cg < 8; ++cg)
        *(u32x4*)&xpose[tid * 128 + ((cg ^ (tid & 7)) << 4)] = dv[cg];
    __syncthreads();

    // emit: wave w, iter it -> 8 pos x 8 cg = 1KB contiguous global write
    const int w = tid >> 6, l = tid & 63, q = l >> 3, cg = l & 7;
    #pragma unroll
    for (int it = 0; it < 8; ++it) {
        int tsrc = w * 64 + it * 8 + q;
        u32x4 c = *(const u32x4*)&xpose[tsrc * 128 + ((cg ^ (tsrc & 7)) << 4)];
        *(u32x4*)((char*)xbz + 128 + ((size_t)(blk2 * 256 + tsrc)) * 128 + cg * 16) = c;
    }
}

// One K-step (pair P = taps 2P,2P+1; K=16 = 2 taps x 8 ch): prefetch pair
// P+1's A (2 reads) + B (2 reads) into 2-slot rings, lgkmcnt(4), then
// 4x mfma_32x32x16 on pair P. All LDS; no global ops in the loop.
// Halo strides: z=160 chunks, y=20, x=1 (chunk = 16B).
template<int P, int PLAST>
__device__ __forceinline__ void kstep2(
    const int (&nbase)[2], int abase, bool thv,
    bf16x8 (&Ar)[2][2], bf16x8 (&Br)[2][2], f32x16 (&acc)[2][2])
{
    if constexpr (P < PLAST) {
        constexpr int Q = P + 1;
        constexpr int t0 = 2 * Q;
        constexpr int t1 = (2 * Q + 1 == 125) ? 124 : 2 * Q + 1;  // B-alias pad tap
        constexpr int dA = ((t0 / 25) * 160 + ((t0 / 5) % 5) * 20 + (t0 % 5)) * 16;
        constexpr int dB = ((t1 / 25) * 160 + ((t1 / 5) % 5) * 20 + (t1 % 5)) * 16;
        #pragma unroll
        for (int mo = 0; mo < 2; ++mo) {
            int a = Q * 2048 + abase + mo * 512;
            asm volatile("ds_read_b128 %0, %1" : "=v"(Ar[Q & 1][mo]) : "v"(a));
        }
        int dsel = thv ? dB : dA;
        #pragma unroll
        for (int np = 0; np < 2; ++np) {
            int a = nbase[np] + dsel;
            asm volatile("ds_read_b128 %0, %1" : "=v"(Br[Q & 1][np]) : "v"(a));
        }
    }
    waitcnt_fence<63, (P < PLAST) ? 4 : 0>();
    #pragma unroll
    for (int mo = 0; mo < 2; ++mo)
        #pragma unroll
        for (int np = 0; np < 2; ++np)
            acc[mo][np] = __builtin_amdgcn_mfma_f32_32x32x16_bf16(
                Ar[P & 1][mo], Br[P & 1][np], acc[mo][np], 0, 0, 0);
    if constexpr (P < PLAST)
        kstep2<P + 1, PLAST>(nbase, abase, thv, Ar, Br, acc);
}

template<int P0, int PLAST>
__device__ __forceinline__ void runphase(
    const int (&nbase)[2], int abase, bool thv, f32x16 (&acc)[2][2])
{
    bf16x8 Ar[2][2], Br[2][2];
    constexpr int t0 = 2 * P0, t1 = 2 * P0 + 1;   // P0 in {0,32}: never 125
    constexpr int dA = ((t0 / 25) * 160 + ((t0 / 5) % 5) * 20 + (t0 % 5)) * 16;
    constexpr int dB = ((t1 / 25) * 160 + ((t1 / 5) % 5) * 20 + (t1 % 5)) * 16;
    #pragma unroll
    for (int mo = 0; mo < 2; ++mo) {
        int a = P0 * 2048 + abase + mo * 512;
        asm volatile("ds_read_b128 %0, %1" : "=v"(Ar[P0 & 1][mo]) : "v"(a));
    }
    int dsel = thv ? dB : dA;
    #pragma unroll
    for (int np = 0; np < 2; ++np) {
        int a = nbase[np] + dsel;
        asm volatile("ds_read_b128 %0, %1" : "=v"(Br[P0 & 1][np]) : "v"(a));
    }
    kstep2<P0, PLAST>(nbase, abase, thv, Ar, Br, acc);
}

// Implicit-GEMM conv, MFMA 32x32x16 bf16, ALL operands from LDS (round-16
// structure, verified 110.3us). grid 256, block 512 thr = 8 waves; tile
// 8z x 4y x 16x = 512 pos, 64 o. Wave = z-plane: 2 mo x 2 np (np = 2y x 16x).
// LDS: Kb stage slice 128 KB (HA/HB ping-pong DMA) + x halo [12z][8y][20x]
// x16B = 30720B. x(s+1) reg-staged (T14).
__global__ __launch_bounds__(512, 1) void conv_mfma(
    const unsigned short* __restrict__ xbz,
    const unsigned short* __restrict__ Kb3,
    float* __restrict__ out)
{
    __shared__ __align__(16) char lds[161792];   // 128K Kb + 30720 x

    const int tid = (int)threadIdx.x;
    const int blk = (int)blockIdx.x;
    const int xt = blk & 1, yt = (blk >> 1) & 7, zt = (blk >> 4) & 3, b = blk >> 6;
    const int lane = tid & 63, wv = tid >> 6;
    const int l31 = lane & 31;
    const bool thv = (lane >= 32);

    // ---- x staging: 1920 chunks of 16B; 4 per thread (wrap duplicates) ----
    unsigned srcOff[4];
    int xdst[4];
    {
        const int gz0 = zt * 8 - 2, gy0 = yt * 4 - 2, gx0 = xt * 16 - 2;
        #pragma unroll
        for (int i = 0; i < 4; ++i) {
            int c = tid + i * 512;
            if (c >= 1920) c -= 1920;
            int hz = c / 160; int rem = c - hz * 160;
            int hy = rem / 20;  int hx = rem - hy * 20;
            int gz = gz0 + hz, gy = gy0 + hy, gx = gx0 + hx;
            bool ok = ((unsigned)gz < 32u) && ((unsigned)gy < 32u) && ((unsigned)gx < 32u);
            int pg = (gz << 10) + (gy << 5) + gx;
            srcOff[i] = ok ? (unsigned)(128 + (((b << 15) + pg) << 7)) : 0u;
            xdst[i] = XB + c * 16;
        }
    }

    // A-frag base: lane row o' = l31, k-half (tap-in-pair) = lane>=32
    const int abase = l31 * 16 + (thv ? 1024 : 0);
    // B-frag bases: pos col n = l31 -> y = (n>>4) + 2*np, x = n&15; z = wv
    int nbase[2];
    #pragma unroll
    for (int np = 0; np < 2; ++np)
        nbase[np] = XB + (wv * 160 + ((l31 >> 4) + 2 * np) * 20 + (l31 & 15)) * 16;

    f32x16 acc[2][2];
    #pragma unroll
    for (int i = 0; i < 2; ++i)
        #pragma unroll
        for (int j = 0; j < 2; ++j) acc[i][j] = (f32x16)0.0f;

    const char* kb = (const char*)Kb3;
    const int kchunk = tid * 16;       // thread's 16B lane within a 64KB half

    // prologue: HA(0) (taps 0..63 of stage 0) + x(0) via DMA
    #pragma unroll
    for (int j = 0; j < 8; ++j) {
        __builtin_amdgcn_global_load_lds(
            (const __attribute__((address_space(1))) unsigned int*)(kb + kchunk + j * 8192),
            (__attribute__((address_space(3))) unsigned int*)(lds + kchunk + j * 8192),
            16, 0, 0);
    }
    #pragma unroll
    for (int i = 0; i < 4; ++i) {
        __builtin_amdgcn_global_load_lds(
            (const __attribute__((address_space(1))) unsigned int*)
                ((const char*)xbz + srcOff[i]),
            (__attribute__((address_space(3))) unsigned int*)(lds + xdst[i]),
            16, 0, 0);
    }

    u32x4 xr[4];   // reg-staged x(s+1)

    #pragma unroll 1
    for (int s = 0; s < 8; ++s) {
        const char* kbs = kb + s * 131072;

        __builtin_amdgcn_s_barrier();               // B1: stage s-1 compute done
        __builtin_amdgcn_sched_barrier(0);
        if (s > 0) {
            waitcnt_fence<8, 15>();                 // xr landed (HA(s) may fly)
            #pragma unroll
            for (int i = 0; i < 4; ++i)
                asm volatile("ds_write_b128 %0, %1" :: "v"(xdst[i]), "v"(xr[i]));
        }
        // HB(s): taps 64..127
        #pragma unroll
        for (int j = 0; j < 8; ++j) {
            __builtin_amdgcn_global_load_lds(
                (const __attribute__((address_space(1))) unsigned int*)
                    (kbs + 65536 + kchunk + j * 8192),
                (__attribute__((address_space(3))) unsigned int*)
                    (lds + 65536 + kchunk + j * 8192),
                16, 0, 0);
        }
        waitcnt_fence<8, 0>();                      // HA(s) (+x) in; writes done
        __builtin_amdgcn_s_barrier();               // B2
        __builtin_amdgcn_sched_barrier(0);

        // xr <- x(s+1), full phase A of latency cover (s=7: dead reload, L2-hot)
        {
            unsigned sx = (unsigned)(((s < 7) ? s + 1 : 7) * 16);
            #pragma unroll
            for (int i = 0; i < 4; ++i) {
                unsigned voff = srcOff[i] + sx;
                asm volatile("global_load_dwordx4 %0, %1, %2"
                             : "=v"(xr[i]) : "v"(voff), "s"(xbz));
            }
            __builtin_amdgcn_sched_barrier(0);
        }

        runphase<0, 31>(nbase, abase, thv, acc);    // pairs 0..31 (HA)

        __builtin_amdgcn_s_barrier();               // B3: HA reads done
        __builtin_amdgcn_sched_barrier(0);
        // HA(s+1) (s=7: harmless overread into ws slack, never consumed)
        #pragma unroll
        for (int j = 0; j < 8; ++j) {
            __builtin_amdgcn_global_load_lds(
                (const __attribute__((address_space(1))) unsigned int*)
                    (kbs + 131072 + kchunk + j * 8192),
                (__attribute__((address_space(3))) unsigned int*)
                    (lds + kchunk + j * 8192),
                16, 0, 0);
        }
        waitcnt_fence<12, 15>();                    // HB(s) landed (xr+HA fly)
        __builtin_amdgcn_s_barrier();               // B4
        __builtin_amdgcn_sched_barrier(0);

        runphase<32, 62>(nbase, abase, thv, acc);   // pairs 32..62 (HB)
    }

    // epilogue: D col = pos = l31, row o' = (reg&3) + 8*(reg>>2) + 4*thv
    const int gz = zt * 8 + wv;
    #pragma unroll
    for (int mo = 0; mo < 2; ++mo) {
        #pragma unroll
        for (int np = 0; np < 2; ++np) {
            const int gy = yt * 4 + 2 * np + (l31 >> 4);
            const int gx = xt * 16 + (l31 & 15);
            #pragma unroll
            for (int reg = 0; reg < 16; ++reg) {
                int o = mo * 32 + (reg & 3) + 8 * (reg >> 2) + (thv ? 4 : 0);
                out[(((size_t)(b * 64 + o)) << 15) + (gz << 10) + (gy << 5) + gx] =
                    0.1f * acc[mo][np][reg];
            }
        }
    }
}

extern "C" void kernel_launch(void* const* d_in, const int* in_sizes, int n_in,
                              void* d_out, int out_size, void* d_ws, size_t ws_size,
                              hipStream_t stream) {
    const float* x       = (const float*)d_in[0];
    const float* w_lin0  = (const float*)d_in[1];
    const float* w_lin1  = (const float*)d_in[2];
    const float* tp      = (const float*)d_in[3];
    unsigned short* Kb3 = (unsigned short*)d_ws;                        // 1 MB (+slack)
    unsigned short* xbz = (unsigned short*)((char*)d_ws + (2u << 20));  // 128B zeros + 16.8MB
    float* out = (float*)d_out;

    prep<<<640, 256, 0, stream>>>(w_lin0, w_lin1, tp, Kb3, x, xbz);
    conv_mfma<<<256, 512, 0, stream>>>(xbz, Kb3, out);
}